// Round 1
// baseline (184.887 us; speedup 1.0000x reference)
//
#include <hip/hip_runtime.h>

#define NBINS 64
#define NCOPIES 64          // one copy per lane of a wave -> zero intra-wave same-address atomics
#define BLOCK 256
#define UNROLL 8            // 8 float4 loads in flight per thread (== entire row at ncols=8192)

// (256,8): 8 waves/SIMD -> 8 blocks/CU resident (LDS 8x16KB=128KB <= 160KB).
// Kernel is pure-streaming HBM-bound; atomics/VALU are ~3x under the BW floor.
__global__ __launch_bounds__(BLOCK, 8) void hist_rows_kernel(
    const float* __restrict__ x, float* __restrict__ out, int ncols) {
    // hist[bin*64 + copy]; copy = tid & 63.
    // Atomic address per lane = bin*64 + lane -> unique within a wave (no RMW serialization).
    // Bank = copy % 32 -> exactly 2-way aliasing across 64 lanes (free, m136).
    __shared__ unsigned int hist[NBINS * NCOPIES];

    const int t = threadIdx.x;
    const int row = blockIdx.x;
    const int copy = t & (NCOPIES - 1);
    const float vmin = -3.0f;
    const float scale = 64.0f / 6.0f;   // fp32, same sub-then-mul order as reference

    const float4* xr = (const float4*)(x + (size_t)row * (size_t)ncols);
    const int nvec = ncols >> 2;

    if (nvec == UNROLL * BLOCK) {
        // Fast path (ncols == 8192): the "loop" is exactly one batch.
        // Issue ALL global loads first; LDS init + barrier run under their latency.
        float4 buf[UNROLL];
        #pragma unroll
        for (int k = 0; k < UNROLL; ++k) buf[k] = xr[k * BLOCK + t];

        // Vectorized zero-init: 4 ds_write_b128 per thread instead of 16 ds_write_b32.
        uint4* h4 = (uint4*)hist;
        #pragma unroll
        for (int i = t; i < (NBINS * NCOPIES) / 4; i += BLOCK)
            h4[i] = make_uint4(0u, 0u, 0u, 0u);
        __syncthreads();

        #pragma unroll
        for (int k = 0; k < UNROLL; ++k) {
            float4 v = buf[k];
            // clamp-in-float then trunc == floor+int-clamp for all non-NaN inputs
            float f0 = __builtin_amdgcn_fmed3f((v.x - vmin) * scale, 0.0f, 63.0f);
            float f1 = __builtin_amdgcn_fmed3f((v.y - vmin) * scale, 0.0f, 63.0f);
            float f2 = __builtin_amdgcn_fmed3f((v.z - vmin) * scale, 0.0f, 63.0f);
            float f3 = __builtin_amdgcn_fmed3f((v.w - vmin) * scale, 0.0f, 63.0f);
            int b0 = (int)f0, b1 = (int)f1, b2 = (int)f2, b3 = (int)f3;
            atomicAdd(&hist[b0 * NCOPIES + copy], 1u);
            atomicAdd(&hist[b1 * NCOPIES + copy], 1u);
            atomicAdd(&hist[b2 * NCOPIES + copy], 1u);
            atomicAdd(&hist[b3 * NCOPIES + copy], 1u);
        }
    } else {
        // Generic fallback for any ncols (not taken at 4096x8192).
        for (int i = t; i < NBINS * NCOPIES; i += BLOCK) hist[i] = 0u;
        __syncthreads();
        for (int i = t; i < nvec; i += BLOCK) {
            float4 v = xr[i];
            float f0 = __builtin_amdgcn_fmed3f((v.x - vmin) * scale, 0.0f, 63.0f);
            float f1 = __builtin_amdgcn_fmed3f((v.y - vmin) * scale, 0.0f, 63.0f);
            float f2 = __builtin_amdgcn_fmed3f((v.z - vmin) * scale, 0.0f, 63.0f);
            float f3 = __builtin_amdgcn_fmed3f((v.w - vmin) * scale, 0.0f, 63.0f);
            atomicAdd(&hist[(int)f0 * NCOPIES + copy], 1u);
            atomicAdd(&hist[(int)f1 * NCOPIES + copy], 1u);
            atomicAdd(&hist[(int)f2 * NCOPIES + copy], 1u);
            atomicAdd(&hist[(int)f3 * NCOPIES + copy], 1u);
        }
        // scalar tail elements (ncols not multiple of 4)
        for (int i = (nvec << 2) + t; i < ncols; i += BLOCK) {
            float f = __builtin_amdgcn_fmed3f(
                (x[(size_t)row * (size_t)ncols + i] - vmin) * scale, 0.0f, 63.0f);
            atomicAdd(&hist[(int)f * NCOPIES + copy], 1u);
        }
    }
    __syncthreads();

    // Parallel epilogue: all 256 threads. Thread t sums 16 copies of bin t>>2,
    // staggered so lane reads rotate banks; butterfly-combine the 4 partials.
    const int bin = t >> 2;          // 0..63
    const int part = t & 3;          // 0..3
    unsigned int s = 0;
    #pragma unroll
    for (int j = 0; j < 16; ++j) {
        const int c = (part * 16 + j + bin) & (NCOPIES - 1);
        s += hist[bin * NCOPIES + c];
    }
    s += __shfl_xor(s, 1);
    s += __shfl_xor(s, 2);
    if (part == 0) {
        const float inv = 1.0f / (float)ncols;
        out[(size_t)row * NBINS + bin] = (float)s * inv;
    }
}

extern "C" void kernel_launch(void* const* d_in, const int* in_sizes, int n_in,
                              void* d_out, int out_size, void* d_ws, size_t ws_size,
                              hipStream_t stream) {
    const float* x = (const float*)d_in[0];
    float* out = (float*)d_out;
    const int nrows = out_size / NBINS;          // 4096
    const int ncols = in_sizes[0] / nrows;       // 8192
    hist_rows_kernel<<<nrows, BLOCK, 0, stream>>>(x, out, ncols);
}